// Round 6
// baseline (66.576 us; speedup 1.0000x reference)
//
#include <hip/hip_runtime.h>
#include <hip/hip_fp16.h>

// Problem constants (from setup_inputs)
#define B_  2
#define C_  256
#define H_  200
#define W_  176
constexpr int HW_ = H_ * W_;             // 35200
constexpr float SCALE_ = 0.25f;

// ---------------------------------------------------------------------------
// Kernel 1: NCHW fp32 -> NHWC fp16 (per batch: [C][HW] -> [HW][C] + convert)
// ---------------------------------------------------------------------------
__global__ __launch_bounds__(256) void nchw_to_nhwc_h(const float* __restrict__ in,
                                                      __half* __restrict__ out) {
    __shared__ float tile[32][65];
    const int b   = blockIdx.z;
    const int hw0 = blockIdx.x * 32;
    const int c0  = blockIdx.y * 64;
    const int tx  = threadIdx.x;     // 0..31  (hw)
    const int ty  = threadIdx.y;     // 0..7

    const float* src = in + (size_t)b * C_ * HW_;
    __half*      dst = out + (size_t)b * HW_ * C_;

#pragma unroll
    for (int jj = 0; jj < 8; ++jj) {
        const int j = ty + jj * 8;
        tile[tx][j] = src[(size_t)(c0 + j) * HW_ + hw0 + tx];
    }
    __syncthreads();

    const int tid  = ty * 32 + tx;
    const int k    = tid & 31;       // c-pair 0..31
    const int row0 = tid >> 5;       // 0..7
#pragma unroll
    for (int rr = 0; rr < 4; ++rr) {
        const int i = row0 + rr * 8;
        __half2 hv;
        hv.x = __float2half(tile[i][2 * k]);
        hv.y = __float2half(tile[i][2 * k + 1]);
        __half2* orow = (__half2*)(dst + (size_t)(hw0 + i) * C_ + c0);
        orow[k] = hv;
    }
}

// ---------------------------------------------------------------------------
// Kernel 2: ROI gather. Grid (N, 2), 256 threads, 8 blocks/CU.
// R5: wide-request restructure. Each wave-load is global_load_dwordx4
// (16 B = 8 channels per lane); lane group lg = lane>>4 picks one of 4
// samples, lanes lc = lane&15 tile the 128-channel half. One instruction
// services 4 samples x 32 channels... i.e. 1 KB/instr, 4x fewer loads.
// Per bin: 4 geo ds_read_b64 + 4 dwordx4 loads + 16 v_pk_fma_f16, then
// cross-group reduce (shfl_xor 16/32) and lanes 0..15 write the bin row.
// Output tile [49][130] fp16 (stride 260 B: copy-out bank-perfect).
// LDS: 6272 + 12740 + 4 ~= 19 KB -> 8 blocks/CU.
// ---------------------------------------------------------------------------
template <bool TR>
__global__ __launch_bounds__(256, 8) void roi_gather(const void* __restrict__ featv,
                                                     const float* __restrict__ rois,
                                                     float* __restrict__ out) {
    __shared__ int2   s_geo[49 * 16];     // {premul byte offset, half2 weight bits}
    __shared__ __half s_tile[49][130];    // [bin][c_local], padded row
    __shared__ int    s_bbase;

    const int n     = blockIdx.x;
    const int chalf = blockIdx.y;
    const int tid   = threadIdx.x;

    if (tid < 196) {
        const float* r = rois + (size_t)n * 8;
        // rois0 columns: [batch, ch, cw, z, rh, rw, z, theta]
        const int   b   = (int)r[0];
        const float chv = r[1] * SCALE_ - 0.5f;
        const float cwv = r[2] * SCALE_ - 0.5f;
        const float rhv = r[4] * SCALE_;
        const float rwv = r[5] * SCALE_;
        // mirror reference's rad->deg->rad round trip (fp32)
        const float deg = r[7] * 57.29577951308232f;
        const float th  = deg * 0.017453292519943295f;
        if (tid == 0) s_bbase = b * C_ * HW_;

        const float bin_h = rhv / 7.0f;
        const float bin_w = rwv / 7.0f;

        const int sp  = tid;        // 0..195
        const int bin = sp >> 2;    // 0..48
        const int s   = sp & 3;
        const int iy  = s >> 1, ix = s & 1;
        const int ph  = bin / 7, pw = bin % 7;

        float yy = -rhv * 0.5f + (float)ph * bin_h + (((float)iy + 0.5f) * bin_h) * 0.5f;
        float xx = -rwv * 0.5f + (float)pw * bin_w + (((float)ix + 0.5f) * bin_w) * 0.5f;

        const float ct = cosf(th), st = sinf(th);
        const float y = yy * ct - xx * st + chv;
        const float x = yy * st + xx * ct + cwv;

        const bool valid = (y >= -1.0f) && (y <= (float)H_) &&
                           (x >= -1.0f) && (x <= (float)W_);
        float yc = fmaxf(y, 0.0f);
        float xc = fmaxf(x, 0.0f);
        int   y0 = (int)floorf(yc);
        int   x0 = (int)floorf(xc);
        if (y0 >= H_ - 1) yc = (float)(H_ - 1);
        if (x0 >= W_ - 1) xc = (float)(W_ - 1);
        y0 = min(y0, H_ - 1);
        x0 = min(x0, W_ - 1);
        const int y1 = min(y0 + 1, H_ - 1);
        const int x1 = min(x0 + 1, W_ - 1);

        const float ly = yc - (float)y0;
        const float lx = xc - (float)x0;
        const float hy = 1.0f - ly, hx = 1.0f - lx;
        const float sc = valid ? 0.25f : 0.0f;   // fold 1/4 mean + validity

        // premultiplied byte offsets (NHWC fp16 row = C*2 = 512 B)
        const int base = TR ? (b * H_) : 0;
        const int o00 = ((base + y0) * W_ + x0) * (TR ? 512 : 1);
        const int o01 = ((base + y0) * W_ + x1) * (TR ? 512 : 1);
        const int o10 = ((base + y1) * W_ + x0) * (TR ? 512 : 1);
        const int o11 = ((base + y1) * W_ + x1) * (TR ? 512 : 1);

        const float w0 = hy * hx * sc, w1 = hy * lx * sc;
        const float w2 = ly * hx * sc, w3 = ly * lx * sc;

        const int e = sp * 4;
        if (TR) {
            __half2 p0 = __half2half2(__float2half(w0));
            __half2 p1 = __half2half2(__float2half(w1));
            __half2 p2 = __half2half2(__float2half(w2));
            __half2 p3 = __half2half2(__float2half(w3));
            s_geo[e + 0] = make_int2(o00, *(int*)&p0);
            s_geo[e + 1] = make_int2(o01, *(int*)&p1);
            s_geo[e + 2] = make_int2(o10, *(int*)&p2);
            s_geo[e + 3] = make_int2(o11, *(int*)&p3);
        } else {
            s_geo[e + 0] = make_int2(o00, __float_as_int(w0));
            s_geo[e + 1] = make_int2(o01, __float_as_int(w1));
            s_geo[e + 2] = make_int2(o10, __float_as_int(w2));
            s_geo[e + 3] = make_int2(o11, __float_as_int(w3));
        }
    }
    __syncthreads();

    const int lane = tid & 63;
    const int wv   = tid >> 6;        // wave id = bin phase 0..3
    const int lg   = lane >> 4;       // sample subgroup 0..3
    const int lc   = lane & 15;       // channel-8-group 0..15

    if (TR) {
        const char* fb = (const char*)featv;
        const unsigned loff = (unsigned)(chalf * 256 + lc * 16);  // lane's 8-ch byte off

        for (int t = 0; t < 13; ++t) {
            const int bin = wv + 4 * t;
            if (bin >= 49) break;     // only wv==0 reaches t==12
            const int e = bin * 16;
            __half2 a0 = __half2half2(__float2half(0.0f));
            __half2 a1 = a0, a2 = a0, a3 = a0;
#pragma unroll
            for (int i = 0; i < 4; ++i) {
                const int2 g = s_geo[e + 4 * i + lg];
                const int4 v = *(const int4*)(fb + ((unsigned)g.x + loff));
                const __half2 w2 = *(const __half2*)&g.y;
                a0 = __hfma2(w2, *(const __half2*)&v.x, a0);
                a1 = __hfma2(w2, *(const __half2*)&v.y, a1);
                a2 = __hfma2(w2, *(const __half2*)&v.z, a2);
                a3 = __hfma2(w2, *(const __half2*)&v.w, a3);
            }
            // combine the 4 sample subgroups: xor 16 then xor 32
#define RED_(A)  {                                                   \
            int t1 = __shfl_xor(*(int*)&(A), 16);                    \
            (A) = __hadd2((A), *(__half2*)&t1);                      \
            int t2 = __shfl_xor(*(int*)&(A), 32);                    \
            (A) = __hadd2((A), *(__half2*)&t2); }
            RED_(a0) RED_(a1) RED_(a2) RED_(a3)
#undef RED_
            if (lg == 0) {
                __half* row = &s_tile[bin][lc * 8];
                *(__half2*)(row + 0) = a0;
                *(__half2*)(row + 2) = a1;
                *(__half2*)(row + 4) = a2;
                *(__half2*)(row + 6) = a3;
            }
        }
    } else {
        // Fallback: fp32 NCHW source, 2 channels per lane (old structure).
        const float* ff = (const float*)featv;
        const int bbase = s_bbase;
        const int cq = lane;
        const int c  = chalf * 128 + 2 * cq;
        for (int bin = wv; bin < 49; bin += 4) {
            float accx = 0.0f, accy = 0.0f;
            const int e = bin * 16;
#pragma unroll
            for (int j = 0; j < 16; ++j) {
                const int2  g = s_geo[e + j];
                const float w = __int_as_float(g.y);
                accx += w * ff[(size_t)(bbase + (chalf * 128 + 2 * cq) * HW_ + g.x)];
                accy += w * ff[(size_t)(bbase + (chalf * 128 + 2 * cq + 1) * HW_ + g.x)];
            }
            s_tile[bin][2 * cq]     = __float2half(accx);
            s_tile[bin][2 * cq + 1] = __float2half(accy);
        }
        (void)c;
    }
    __syncthreads();

    // Copy-out: output-linear (c-major); tile reads walk banks (stride 260 B).
    float* ob = out + (size_t)n * (C_ * 49) + (size_t)chalf * (128 * 49);
    for (int i = tid; i < 128 * 49; i += 256) {
        const int c = i / 49, bn = i % 49;
        ob[i] = __half2float(s_tile[bn][c]);
    }
}

extern "C" void kernel_launch(void* const* d_in, const int* in_sizes, int n_in,
                              void* d_out, int out_size, void* d_ws, size_t ws_size,
                              hipStream_t stream) {
    const float* x    = (const float*)d_in[0];
    const float* rois = (const float*)d_in[1];
    float*       out  = (float*)d_out;
    const int N = in_sizes[1] / 8;

    const size_t tr_bytes = (size_t)B_ * HW_ * C_ * sizeof(__half);
    if (ws_size >= tr_bytes) {
        __half* xt = (__half*)d_ws;
        dim3 tb(32, 8);
        dim3 tg(HW_ / 32, C_ / 64, B_);
        nchw_to_nhwc_h<<<tg, tb, 0, stream>>>(x, xt);
        dim3 gg(N, 2);
        roi_gather<true><<<gg, 256, 0, stream>>>(xt, rois, out);
    } else {
        dim3 gg(N, 2);
        roi_gather<false><<<gg, 256, 0, stream>>>(x, rois, out);
    }
}

// Round 7
// 54.471 us; speedup vs baseline: 1.2222x; 1.2222x over previous
//
#include <hip/hip_runtime.h>
#include <hip/hip_fp16.h>

// Problem constants (from setup_inputs)
#define B_  2
#define C_  256
#define H_  200
#define W_  176
constexpr int HW_ = H_ * W_;             // 35200
constexpr float SCALE_ = 0.25f;

// ---------------------------------------------------------------------------
// Kernel 0: spatial-bucket permutation. 8 buckets = batch(2) x quadrant(4),
// each bucket's feature region ~4.5 MB ~ one XCD's L2. Dispatch slot s with
// s%8==g gets a bucket-g roi => spatially-overlapping rois share an XCD L2
// (workgroup->XCD is round-robin on linear wgid). Slot order within a bucket
// is atomic-nondeterministic, but every roi writes only its own output rows,
// so final output bytes are identical regardless of assignment.
// ---------------------------------------------------------------------------
__global__ __launch_bounds__(1024) void build_perm(const float* __restrict__ rois,
                                                   int N, int* __restrict__ perm) {
    __shared__ int fill[8];
    __shared__ int spill_roi[1024];
    __shared__ int spill_cnt;
    const int tid = threadIdx.x;
    if (tid < 8) fill[tid] = 0;
    if (tid == 0) spill_cnt = 0;
    __syncthreads();

    if (N > 1024 || (N & 7) != 0) {          // fallback: identity
        for (int i = tid; i < N; i += 1024) perm[i] = i;
        return;
    }
    const int S = N >> 3;                     // slots per residue class

    int bk = -1;
    if (tid < N) {
        const float* r = rois + (size_t)tid * 8;
        const int   b  = (int)r[0];
        const float cy = r[1] * SCALE_;       // feature-space center y
        const float cx = r[2] * SCALE_;       // feature-space center x
        bk = b * 4 + (cy >= (float)H_ * 0.5f ? 2 : 0) + (cx >= (float)W_ * 0.5f ? 1 : 0);
        const int rank = atomicAdd(&fill[bk], 1);
        if (rank < S) perm[bk + 8 * rank] = tid;
        else          spill_roi[atomicAdd(&spill_cnt, 1)] = tid;
    }
    __syncthreads();
    if (tid == 0) {
        int idx = 0;
        for (int g = 0; g < 8; ++g) {
            const int have = fill[g] < S ? fill[g] : S;
            for (int r = have; r < S; ++r) perm[g + 8 * r] = spill_roi[idx++];
        }
    }
}

// ---------------------------------------------------------------------------
// Kernel 1: NCHW fp32 -> NHWC fp16 (per batch: [C][HW] -> [HW][C] + convert)
// ---------------------------------------------------------------------------
__global__ __launch_bounds__(256) void nchw_to_nhwc_h(const float* __restrict__ in,
                                                      __half* __restrict__ out) {
    __shared__ float tile[32][65];
    const int b   = blockIdx.z;
    const int hw0 = blockIdx.x * 32;
    const int c0  = blockIdx.y * 64;
    const int tx  = threadIdx.x;     // 0..31  (hw)
    const int ty  = threadIdx.y;     // 0..7

    const float* src = in + (size_t)b * C_ * HW_;
    __half*      dst = out + (size_t)b * HW_ * C_;

#pragma unroll
    for (int jj = 0; jj < 8; ++jj) {
        const int j = ty + jj * 8;
        tile[tx][j] = src[(size_t)(c0 + j) * HW_ + hw0 + tx];
    }
    __syncthreads();

    const int tid  = ty * 32 + tx;
    const int k    = tid & 31;       // c-pair 0..31
    const int row0 = tid >> 5;       // 0..7
#pragma unroll
    for (int rr = 0; rr < 4; ++rr) {
        const int i = row0 + rr * 8;
        __half2 hv;
        hv.x = __float2half(tile[i][2 * k]);
        hv.y = __float2half(tile[i][2 * k + 1]);
        __half2* orow = (__half2*)(dst + (size_t)(hw0 + i) * C_ + c0);
        orow[k] = hv;
    }
}

// ---------------------------------------------------------------------------
// Kernel 2: ROI gather (R4 structure + perm indirection). Grid (N, 2),
// 256 threads, 8 blocks/CU. Hot loop per sample: ds_read_b64 broadcast +
// v_add + global_load_dword (half2 = 2 ch) + v_pk_fma_f16.
// ---------------------------------------------------------------------------
template <bool TR>
__global__ __launch_bounds__(256, 8) void roi_gather(const void* __restrict__ featv,
                                                     const float* __restrict__ rois,
                                                     const int* __restrict__ perm,
                                                     float* __restrict__ out) {
    __shared__ int2   s_geo[49 * 16];     // {premul byte offset, half2 weight bits}
    __shared__ __half s_tile[128 * 49];   // [c_local][bin]
    __shared__ int    s_bbase;

    const int n     = TR ? perm[blockIdx.x] : blockIdx.x;
    const int chalf = blockIdx.y;
    const int tid   = threadIdx.x;

    if (tid < 196) {
        const float* r = rois + (size_t)n * 8;
        // rois0 columns: [batch, ch, cw, z, rh, rw, z, theta]
        const int   b   = (int)r[0];
        const float chv = r[1] * SCALE_ - 0.5f;
        const float cwv = r[2] * SCALE_ - 0.5f;
        const float rhv = r[4] * SCALE_;
        const float rwv = r[5] * SCALE_;
        // mirror reference's rad->deg->rad round trip (fp32)
        const float deg = r[7] * 57.29577951308232f;
        const float th  = deg * 0.017453292519943295f;
        if (tid == 0) s_bbase = b * C_ * HW_;

        const float bin_h = rhv / 7.0f;
        const float bin_w = rwv / 7.0f;

        const int sp  = tid;        // 0..195
        const int bin = sp >> 2;    // 0..48
        const int s   = sp & 3;
        const int iy  = s >> 1, ix = s & 1;
        const int ph  = bin / 7, pw = bin % 7;

        float yy = -rhv * 0.5f + (float)ph * bin_h + (((float)iy + 0.5f) * bin_h) * 0.5f;
        float xx = -rwv * 0.5f + (float)pw * bin_w + (((float)ix + 0.5f) * bin_w) * 0.5f;

        const float ct = cosf(th), st = sinf(th);
        const float y = yy * ct - xx * st + chv;
        const float x = yy * st + xx * ct + cwv;

        const bool valid = (y >= -1.0f) && (y <= (float)H_) &&
                           (x >= -1.0f) && (x <= (float)W_);
        float yc = fmaxf(y, 0.0f);
        float xc = fmaxf(x, 0.0f);
        int   y0 = (int)floorf(yc);
        int   x0 = (int)floorf(xc);
        if (y0 >= H_ - 1) yc = (float)(H_ - 1);
        if (x0 >= W_ - 1) xc = (float)(W_ - 1);
        y0 = min(y0, H_ - 1);
        x0 = min(x0, W_ - 1);
        const int y1 = min(y0 + 1, H_ - 1);
        const int x1 = min(x0 + 1, W_ - 1);

        const float ly = yc - (float)y0;
        const float lx = xc - (float)x0;
        const float hy = 1.0f - ly, hx = 1.0f - lx;
        const float sc = valid ? 0.25f : 0.0f;   // fold 1/4 mean + validity

        // premultiplied byte offsets (NHWC fp16 row = C*2 = 512 B)
        const int base = TR ? (b * H_) : 0;
        const int o00 = ((base + y0) * W_ + x0) * (TR ? 512 : 1);
        const int o01 = ((base + y0) * W_ + x1) * (TR ? 512 : 1);
        const int o10 = ((base + y1) * W_ + x0) * (TR ? 512 : 1);
        const int o11 = ((base + y1) * W_ + x1) * (TR ? 512 : 1);

        const float w0 = hy * hx * sc, w1 = hy * lx * sc;
        const float w2 = ly * hx * sc, w3 = ly * lx * sc;

        const int e = sp * 4;
        if (TR) {
            __half2 p0 = __half2half2(__float2half(w0));
            __half2 p1 = __half2half2(__float2half(w1));
            __half2 p2 = __half2half2(__float2half(w2));
            __half2 p3 = __half2half2(__float2half(w3));
            s_geo[e + 0] = make_int2(o00, *(int*)&p0);
            s_geo[e + 1] = make_int2(o01, *(int*)&p1);
            s_geo[e + 2] = make_int2(o10, *(int*)&p2);
            s_geo[e + 3] = make_int2(o11, *(int*)&p3);
        } else {
            s_geo[e + 0] = make_int2(o00, __float_as_int(w0));
            s_geo[e + 1] = make_int2(o01, __float_as_int(w1));
            s_geo[e + 2] = make_int2(o10, __float_as_int(w2));
            s_geo[e + 3] = make_int2(o11, __float_as_int(w3));
        }
    }
    __syncthreads();

    const int cq = tid & 63;                  // channel-pair index within half
    const int wv = tid >> 6;                  // wave id = bin phase 0..3
    const int bbase = s_bbase;

    const char*  fb   = (const char*)featv;       // NHWC fp16 (byte addressed)
    const float* ff   = (const float*)featv;      // NCHW fp32 fallback
    const unsigned loff = (unsigned)(chalf * 64 + cq) * 4u;  // lane channel byte
    const int    c    = chalf * 128 + 2 * cq;     // fallback channels

    for (int bin = wv; bin < 49; bin += 4) {
        const int e = bin * 16;
        if (TR) {
            __half2 acc = __half2half2(__float2half(0.0f));
#pragma unroll
            for (int j = 0; j < 16; ++j) {
                const int2 g = s_geo[e + j];
                const __half2 hv = *(const __half2*)(fb + ((unsigned)g.x + loff));
                const __half2 w2 = *(const __half2*)&g.y;
                acc = __hfma2(w2, hv, acc);
            }
            s_tile[(2 * cq) * 49 + bin]     = __low2half(acc);
            s_tile[(2 * cq + 1) * 49 + bin] = __high2half(acc);
        } else {
            float accx = 0.0f, accy = 0.0f;
#pragma unroll
            for (int j = 0; j < 16; ++j) {
                const int2  g = s_geo[e + j];
                const float w = __int_as_float(g.y);
                accx += w * ff[(size_t)(bbase + c * HW_ + g.x)];
                accy += w * ff[(size_t)(bbase + (c + 1) * HW_ + g.x)];
            }
            s_tile[(2 * cq) * 49 + bin]     = __float2half(accx);
            s_tile[(2 * cq + 1) * 49 + bin] = __float2half(accy);
        }
    }
    __syncthreads();

    // Copy-out: 6272 halfs -> f32, 4B/lane coalesced stores.
    float* ob = out + (size_t)n * (C_ * 49) + (size_t)chalf * (128 * 49);
    for (int i = tid; i < 128 * 49; i += 256) ob[i] = __half2float(s_tile[i]);
}

extern "C" void kernel_launch(void* const* d_in, const int* in_sizes, int n_in,
                              void* d_out, int out_size, void* d_ws, size_t ws_size,
                              hipStream_t stream) {
    const float* x    = (const float*)d_in[0];
    const float* rois = (const float*)d_in[1];
    float*       out  = (float*)d_out;
    const int N = in_sizes[1] / 8;

    const size_t tr_bytes = (size_t)B_ * HW_ * C_ * sizeof(__half);
    const size_t perm_bytes = (size_t)N * sizeof(int);
    if (ws_size >= tr_bytes + perm_bytes && N <= 1024) {
        __half* xt   = (__half*)d_ws;
        int*    perm = (int*)((char*)d_ws + tr_bytes);
        build_perm<<<1, 1024, 0, stream>>>(rois, N, perm);
        dim3 tb(32, 8);
        dim3 tg(HW_ / 32, C_ / 64, B_);
        nchw_to_nhwc_h<<<tg, tb, 0, stream>>>(x, xt);
        dim3 gg(N, 2);
        roi_gather<true><<<gg, 256, 0, stream>>>(xt, rois, perm, out);
    } else {
        dim3 gg(N, 2);
        roi_gather<false><<<gg, 256, 0, stream>>>(x, rois, nullptr, out);
    }
}

// Round 8
// 47.594 us; speedup vs baseline: 1.3988x; 1.1445x over previous
//
#include <hip/hip_runtime.h>
#include <hip/hip_fp16.h>

// Problem constants (from setup_inputs)
#define B_  2
#define C_  256
#define H_  200
#define W_  176
constexpr int HW_ = H_ * W_;             // 35200
constexpr float SCALE_ = 0.25f;

// ---------------------------------------------------------------------------
// Kernel 1: NCHW fp32 -> NHWC fp16 transpose, with the spatial-bucket
// permutation fused into block (0,0,0) (saves a serialized kernel launch).
// Buckets: 8 = batch(2) x quadrant(4); dispatch slot s with s%8==g gets a
// bucket-g roi so spatially-overlapping rois share an XCD L2 (workgroup->XCD
// is round-robin on linear wgid). Slot order within a bucket is atomic-
// nondeterministic but each roi writes only its own output rows -> output
// bytes deterministic.
// ---------------------------------------------------------------------------
__global__ __launch_bounds__(256) void nchw_to_nhwc_h(const float* __restrict__ in,
                                                      __half* __restrict__ out,
                                                      const float* __restrict__ rois,
                                                      int N, int* __restrict__ perm) {
    __shared__ float tile[32][65];
    __shared__ int   fill[8];
    __shared__ int   spill[1024];
    __shared__ int   spill_cnt;

    const int b   = blockIdx.z;
    const int hw0 = blockIdx.x * 32;
    const int c0  = blockIdx.y * 64;
    const int tx  = threadIdx.x;     // 0..31  (hw)
    const int ty  = threadIdx.y;     // 0..7

    const float* src = in + (size_t)b * C_ * HW_;
    __half*      dst = out + (size_t)b * HW_ * C_;

#pragma unroll
    for (int jj = 0; jj < 8; ++jj) {
        const int j = ty + jj * 8;
        tile[tx][j] = src[(size_t)(c0 + j) * HW_ + hw0 + tx];
    }
    __syncthreads();

    const int tid  = ty * 32 + tx;
    const int k    = tid & 31;       // c-pair 0..31
    const int row0 = tid >> 5;       // 0..7
#pragma unroll
    for (int rr = 0; rr < 4; ++rr) {
        const int i = row0 + rr * 8;
        __half2 hv;
        hv.x = __float2half(tile[i][2 * k]);
        hv.y = __float2half(tile[i][2 * k + 1]);
        __half2* orow = (__half2*)(dst + (size_t)(hw0 + i) * C_ + c0);
        orow[k] = hv;
    }

    // ---- fused perm build (block-uniform branch; syncthreads are safe) ----
    if (blockIdx.x == 0 && blockIdx.y == 0 && blockIdx.z == 0) {
        if (tid < 8) fill[tid] = 0;
        if (tid == 0) spill_cnt = 0;
        __syncthreads();
        if (N > 1024 || (N & 7) != 0) {      // fallback: identity
            for (int i = tid; i < N; i += 256) perm[i] = i;
            return;
        }
        const int S = N >> 3;                 // slots per residue class
        for (int i = tid; i < N; i += 256) {
            const float* r = rois + (size_t)i * 8;
            const int   rb = (int)r[0];
            const float cy = r[1] * SCALE_;   // feature-space center y
            const float cx = r[2] * SCALE_;   // feature-space center x
            const int bk = rb * 4 + (cy >= (float)H_ * 0.5f ? 2 : 0)
                                  + (cx >= (float)W_ * 0.5f ? 1 : 0);
            const int rank = atomicAdd(&fill[bk], 1);
            if (rank < S) perm[bk + 8 * rank] = i;
            else          spill[atomicAdd(&spill_cnt, 1)] = i;
        }
        __syncthreads();
        if (tid == 0) {
            int idx = 0;
            for (int g = 0; g < 8; ++g) {
                const int have = fill[g] < S ? fill[g] : S;
                for (int r = have; r < S; ++r) perm[g + 8 * r] = spill[idx++];
            }
        }
    }
}

// ---------------------------------------------------------------------------
// Kernel 2: ROI gather (R4 structure + perm indirection). Grid (N, 2),
// 256 threads, 8 blocks/CU. Hot loop per sample: ds_read_b64 broadcast +
// v_add + global_load_dword (half2 = 2 ch) + v_pk_fma_f16.
// Copy-out uses non-temporal stores: output is never re-read, keep it from
// evicting the XCD-local feature working set in L2.
// ---------------------------------------------------------------------------
template <bool TR>
__global__ __launch_bounds__(256, 8) void roi_gather(const void* __restrict__ featv,
                                                     const float* __restrict__ rois,
                                                     const int* __restrict__ perm,
                                                     float* __restrict__ out) {
    __shared__ int2   s_geo[49 * 16];     // {premul byte offset, half2 weight bits}
    __shared__ __half s_tile[128 * 49];   // [c_local][bin]
    __shared__ int    s_bbase;

    const int n     = TR ? perm[blockIdx.x] : blockIdx.x;
    const int chalf = blockIdx.y;
    const int tid   = threadIdx.x;

    if (tid < 196) {
        const float* r = rois + (size_t)n * 8;
        // rois0 columns: [batch, ch, cw, z, rh, rw, z, theta]
        const int   b   = (int)r[0];
        const float chv = r[1] * SCALE_ - 0.5f;
        const float cwv = r[2] * SCALE_ - 0.5f;
        const float rhv = r[4] * SCALE_;
        const float rwv = r[5] * SCALE_;
        // mirror reference's rad->deg->rad round trip (fp32)
        const float deg = r[7] * 57.29577951308232f;
        const float th  = deg * 0.017453292519943295f;
        if (tid == 0) s_bbase = b * C_ * HW_;

        const float bin_h = rhv / 7.0f;
        const float bin_w = rwv / 7.0f;

        const int sp  = tid;        // 0..195
        const int bin = sp >> 2;    // 0..48
        const int s   = sp & 3;
        const int iy  = s >> 1, ix = s & 1;
        const int ph  = bin / 7, pw = bin % 7;

        float yy = -rhv * 0.5f + (float)ph * bin_h + (((float)iy + 0.5f) * bin_h) * 0.5f;
        float xx = -rwv * 0.5f + (float)pw * bin_w + (((float)ix + 0.5f) * bin_w) * 0.5f;

        const float ct = cosf(th), st = sinf(th);
        const float y = yy * ct - xx * st + chv;
        const float x = yy * st + xx * ct + cwv;

        const bool valid = (y >= -1.0f) && (y <= (float)H_) &&
                           (x >= -1.0f) && (x <= (float)W_);
        float yc = fmaxf(y, 0.0f);
        float xc = fmaxf(x, 0.0f);
        int   y0 = (int)floorf(yc);
        int   x0 = (int)floorf(xc);
        if (y0 >= H_ - 1) yc = (float)(H_ - 1);
        if (x0 >= W_ - 1) xc = (float)(W_ - 1);
        y0 = min(y0, H_ - 1);
        x0 = min(x0, W_ - 1);
        const int y1 = min(y0 + 1, H_ - 1);
        const int x1 = min(x0 + 1, W_ - 1);

        const float ly = yc - (float)y0;
        const float lx = xc - (float)x0;
        const float hy = 1.0f - ly, hx = 1.0f - lx;
        const float sc = valid ? 0.25f : 0.0f;   // fold 1/4 mean + validity

        // premultiplied byte offsets (NHWC fp16 row = C*2 = 512 B)
        const int base = TR ? (b * H_) : 0;
        const int o00 = ((base + y0) * W_ + x0) * (TR ? 512 : 1);
        const int o01 = ((base + y0) * W_ + x1) * (TR ? 512 : 1);
        const int o10 = ((base + y1) * W_ + x0) * (TR ? 512 : 1);
        const int o11 = ((base + y1) * W_ + x1) * (TR ? 512 : 1);

        const float w0 = hy * hx * sc, w1 = hy * lx * sc;
        const float w2 = ly * hx * sc, w3 = ly * lx * sc;

        const int e = sp * 4;
        if (TR) {
            __half2 p0 = __half2half2(__float2half(w0));
            __half2 p1 = __half2half2(__float2half(w1));
            __half2 p2 = __half2half2(__float2half(w2));
            __half2 p3 = __half2half2(__float2half(w3));
            s_geo[e + 0] = make_int2(o00, *(int*)&p0);
            s_geo[e + 1] = make_int2(o01, *(int*)&p1);
            s_geo[e + 2] = make_int2(o10, *(int*)&p2);
            s_geo[e + 3] = make_int2(o11, *(int*)&p3);
        } else {
            s_geo[e + 0] = make_int2(o00, __float_as_int(w0));
            s_geo[e + 1] = make_int2(o01, __float_as_int(w1));
            s_geo[e + 2] = make_int2(o10, __float_as_int(w2));
            s_geo[e + 3] = make_int2(o11, __float_as_int(w3));
        }
    }
    __syncthreads();

    const int cq = tid & 63;                  // channel-pair index within half
    const int wv = tid >> 6;                  // wave id = bin phase 0..3
    const int bbase = s_bbase;

    const char*  fb   = (const char*)featv;       // NHWC fp16 (byte addressed)
    const float* ff   = (const float*)featv;      // NCHW fp32 fallback
    const unsigned loff = (unsigned)(chalf * 64 + cq) * 4u;  // lane channel byte
    const int    c    = chalf * 128 + 2 * cq;     // fallback channels

    for (int bin = wv; bin < 49; bin += 4) {
        const int e = bin * 16;
        if (TR) {
            __half2 acc = __half2half2(__float2half(0.0f));
#pragma unroll
            for (int j = 0; j < 16; ++j) {
                const int2 g = s_geo[e + j];
                const __half2 hv = *(const __half2*)(fb + ((unsigned)g.x + loff));
                const __half2 w2 = *(const __half2*)&g.y;
                acc = __hfma2(w2, hv, acc);
            }
            s_tile[(2 * cq) * 49 + bin]     = __low2half(acc);
            s_tile[(2 * cq + 1) * 49 + bin] = __high2half(acc);
        } else {
            float accx = 0.0f, accy = 0.0f;
#pragma unroll
            for (int j = 0; j < 16; ++j) {
                const int2  g = s_geo[e + j];
                const float w = __int_as_float(g.y);
                accx += w * ff[(size_t)(bbase + c * HW_ + g.x)];
                accy += w * ff[(size_t)(bbase + (c + 1) * HW_ + g.x)];
            }
            s_tile[(2 * cq) * 49 + bin]     = __float2half(accx);
            s_tile[(2 * cq + 1) * 49 + bin] = __float2half(accy);
        }
    }
    __syncthreads();

    // Copy-out: 6272 halfs -> f32, 4B/lane coalesced non-temporal stores.
    float* ob = out + (size_t)n * (C_ * 49) + (size_t)chalf * (128 * 49);
    for (int i = tid; i < 128 * 49; i += 256) {
        __builtin_nontemporal_store(__half2float(s_tile[i]), &ob[i]);
    }
}

extern "C" void kernel_launch(void* const* d_in, const int* in_sizes, int n_in,
                              void* d_out, int out_size, void* d_ws, size_t ws_size,
                              hipStream_t stream) {
    const float* x    = (const float*)d_in[0];
    const float* rois = (const float*)d_in[1];
    float*       out  = (float*)d_out;
    const int N = in_sizes[1] / 8;

    const size_t tr_bytes = (size_t)B_ * HW_ * C_ * sizeof(__half);
    const size_t perm_bytes = (size_t)N * sizeof(int);
    if (ws_size >= tr_bytes + perm_bytes && N <= 1024) {
        __half* xt   = (__half*)d_ws;
        int*    perm = (int*)((char*)d_ws + tr_bytes);
        dim3 tb(32, 8);
        dim3 tg(HW_ / 32, C_ / 64, B_);
        nchw_to_nhwc_h<<<tg, tb, 0, stream>>>(x, xt, rois, N, perm);
        dim3 gg(N, 2);
        roi_gather<true><<<gg, 256, 0, stream>>>(xt, rois, perm, out);
    } else {
        dim3 gg(N, 2);
        roi_gather<false><<<gg, 256, 0, stream>>>(x, rois, nullptr, out);
    }
}